// Round 2
// baseline (1038.116 us; speedup 1.0000x reference)
//
#include <hip/hip_runtime.h>

#define BATCH 32
#define CIN_  64
#define COUT_ 64
#define H_    224
#define W_    224
#define HW_   (H_*W_)

#define HT     2            // output rows per tile
#define WTILE  112          // output cols per block
#define XS_P   116          // padded pixels per LDS row (need 114)
#define NG     7            // N-groups of 32 outputs (2 rows x 16 px)
#define HSTRIP 28           // tiles per block (56 output rows)
#define ROWSZ  (XS_P*64)    // bf16 elems per LDS row slot

typedef __bf16 bf16x4 __attribute__((ext_vector_type(4)));
typedef __bf16 bf16x8 __attribute__((ext_vector_type(8)));
typedef float  f32x16 __attribute__((ext_vector_type(16)));

// Binarize weights: wp[tap][co][ci] = bf16(sign(w[co][ci][tap]))
__global__ void bc_prep(const float* __restrict__ w, __bf16* __restrict__ wp) {
    int gid = blockIdx.x * 256 + threadIdx.x;
    if (gid >= COUT_ * CIN_ * 9) return;
    int co  = gid / (CIN_ * 9);
    int rem = gid - co * (CIN_ * 9);
    int ci  = rem / 9;
    int t   = rem - ci * 9;
    float v = w[gid];
    float s = (v > 0.0f) ? 1.0f : ((v < 0.0f) ? -1.0f : 0.0f);
    wp[t * (COUT_ * CIN_) + co * CIN_ + ci] = (__bf16)s;
}

// Persistent-strip implicit-GEMM binary conv, 32x32x16 MFMA.
// Block: 512 thr (8 waves), owns (b, w-half, 56-row strip) = 28 tiles of 2 rows.
// LDS: 4-slot row ring (slot = input_row & 3), XOR-swizzled [px][ci] layout.
// Pipeline (T14): issue global loads for tile t+2 -> regs before barrier;
// they fly across compute(t+1); convert+ds_write after the next barrier.
__global__ __launch_bounds__(512, 2)
void bc_main(const float* __restrict__ x, const __bf16* __restrict__ wp,
             const float* __restrict__ bias, float* __restrict__ out) {
    __shared__ __attribute__((aligned(16))) __bf16 xs[4 * ROWSZ];

    const int hs = blockIdx.x;        // 0..3 strip
    const int wt = blockIdx.y;        // 0..1
    const int bb = blockIdx.z;        // 0..31
    const int h0 = hs * (HSTRIP * HT);
    const int w0 = wt * WTILE;

    const int tid  = threadIdx.x;
    const int lane = tid & 63;
    const int wave = tid >> 6;        // 0..7
    const int ct   = wave & 1;        // co-tile (32 co each)
    const int gsel = wave >> 1;       // group selector 0..3
    const int col  = lane & 31;
    const int kh   = lane >> 5;       // k half (ci +0 / +8)

    // ---- A fragments: A[m=col][k=kh*8+j], k-step s: tap=s>>2, ci=(s&3)*16 ----
    bf16x8 afrag[36];
    {
        const int m = ct * 32 + col;
        #pragma unroll
        for (int s = 0; s < 36; ++s) {
            const int tap = s >> 2;
            const int cib = (s & 3) * 16 + kh * 8;
            afrag[s] = *(const bf16x8*)(wp + tap * (COUT_ * CIN_) + m * CIN_ + cib);
        }
    }
    float biasr[16];
    #pragma unroll
    for (int r = 0; r < 16; ++r)
        biasr[r] = bias[ct * 32 + 4 * kh + (r & 3) + 8 * (r >> 2)];

    // ---- staging thread mapping: 2 rows x (32 pxg x 16 cig) over 512 thr ----
    const int rsel  = tid >> 8;        // which of the 2 rows
    const int t8    = tid & 255;
    const int pxg0  = t8 & 15;         // + s*16 -> pxg 0..31
    const int cig   = t8 >> 4;         // 0..15 : 4-ci group
    const int ci0   = cig * 4;
    const int cc    = cig >> 1;        // 8-ci chunk index 0..7
    const int chalf = (cig & 1) * 4;   // offset inside chunk

    float pb[2][4][4];                 // [s][j=ci][i=px] pipeline reg buffer

    // issue global loads for rows (rowbase, rowbase+1) into pb (no waits here)
    auto issue2 = [&](int rowbase) {
        const int hin = rowbase + rsel;
        const bool rowok = (hin >= 0) && (hin < H_);
        const float* src = x + (size_t)bb * CIN_ * HW_ + (size_t)hin * W_;
        #pragma unroll
        for (int s = 0; s < 2; ++s) {
            const int wbase = w0 - 4 + (pxg0 + s * 16) * 4;
            #pragma unroll
            for (int j = 0; j < 4; ++j) {
                const float* pr = src + (size_t)(ci0 + j) * HW_ + wbase;
                if (rowok && wbase >= 0 && wbase + 3 < W_) {
                    float4 f = *(const float4*)pr;
                    pb[s][j][0] = f.x; pb[s][j][1] = f.y;
                    pb[s][j][2] = f.z; pb[s][j][3] = f.w;
                } else {
                    #pragma unroll
                    for (int i = 0; i < 4; ++i) {
                        const int wg = wbase + i;
                        pb[s][j][i] = (rowok && wg >= 0 && wg < W_) ? pr[i] : 0.0f;
                    }
                }
            }
        }
    };

    // convert pb -> bf16 and write into ring slot of (rowbase, rowbase+1)
    auto commit2 = [&](int rowbase) {
        const int slot = (rowbase + rsel) & 3;
        __bf16* dst = xs + slot * ROWSZ;
        #pragma unroll
        for (int s = 0; s < 2; ++s) {
            const int pxg = pxg0 + s * 16;
            #pragma unroll
            for (int i = 0; i < 4; ++i) {
                const int p = pxg * 4 + i - 3;
                if (p >= 0 && p < XS_P) {
                    bf16x4 pk;
                    pk[0] = (__bf16)pb[s][0][i];
                    pk[1] = (__bf16)pb[s][1][i];
                    pk[2] = (__bf16)pb[s][2][i];
                    pk[3] = (__bf16)pb[s][3][i];
                    const int cp = cc ^ ((p >> 1) & 7);
                    *(bf16x4*)&dst[p * 64 + cp * 8 + chalf] = pk;
                }
            }
        }
    };

    // ---- prologue: fill ring with rows h0-1 .. h0+2, prefetch h0+3,h0+4 ----
    issue2(h0 - 1); commit2(h0 - 1);
    issue2(h0 + 1); commit2(h0 + 1);
    issue2(h0 + 3);                    // in flight across first compute
    __syncthreads();

    // ---- compute constants ----
    const int hh  = col >> 4;          // output row within group
    const int pxl = col & 15;          // output col within group
    int swz[3];
    #pragma unroll
    for (int dw = 0; dw < 3; ++dw) swz[dw] = ((pxl + dw) >> 1) & 7;

    #pragma unroll 1
    for (int t = 0; t < HSTRIP; ++t) {
        const int h0t = h0 + 2 * t;
        int rbase[3];                  // LDS row-slot base per dh
        #pragma unroll
        for (int dh = 0; dh < 3; ++dh)
            rbase[dh] = ((h0t - 1 + hh + dh) & 3) * ROWSZ;

        for (int g = gsel; g < NG; g += 4) {
            f32x16 acc = {};
            #pragma unroll
            for (int s = 0; s < 36; ++s) {
                const int tap = s >> 2;
                const int dh  = tap / 3;
                const int dw  = tap - dh * 3;
                const int c   = (s & 3) * 2 + kh;
                const int cp  = c ^ swz[dw];
                const int pin = g * 16 + pxl + dw;
                const bf16x8* bsrc =
                    (const bf16x8*)&xs[rbase[dh] + pin * 64 + cp * 8];
                acc = __builtin_amdgcn_mfma_f32_32x32x16_bf16(afrag[s], *bsrc, acc, 0, 0, 0);
            }
            float* op = out + ((size_t)bb * COUT_ + ct * 32 + 4 * kh) * (size_t)HW_
                            + (size_t)(h0t + hh) * W_ + (w0 + g * 16 + pxl);
            #pragma unroll
            for (int r = 0; r < 16; ++r) {
                const int co_r = (r & 3) + 8 * (r >> 2);
                op[(size_t)co_r * HW_] = acc[r] + biasr[r];
            }
        }

        if (t == HSTRIP - 1) break;
        __syncthreads();               // everyone done reading old slots
        commit2(h0t + 3);              // rows for tile t+1 (vmcnt waits here)
        if (t < HSTRIP - 2) issue2(h0t + 5);   // rows for tile t+2, fly over next compute
        __syncthreads();               // commits visible
    }
}

extern "C" void kernel_launch(void* const* d_in, const int* in_sizes, int n_in,
                              void* d_out, int out_size, void* d_ws, size_t ws_size,
                              hipStream_t stream) {
    const float* x    = (const float*)d_in[0];
    const float* w    = (const float*)d_in[1];
    const float* bias = (const float*)d_in[2];
    float* out = (float*)d_out;
    __bf16* wp = (__bf16*)d_ws;   // 9*64*64*2 = 73728 B

    bc_prep<<<dim3((COUT_ * CIN_ * 9 + 255) / 256), dim3(256), 0, stream>>>(w, wp);
    bc_main<<<dim3(224 / (HSTRIP * HT), W_ / WTILE, BATCH), dim3(512), 0, stream>>>(x, wp, bias, out);
}